// Round 1
// baseline (503.561 us; speedup 1.0000x reference)
//
#include <hip/hip_runtime.h>

#define N_NODES 100000
#define N_EDGES 1600000

// ---------------- row_ptr via binary search over sorted dst ----------------
__global__ __launch_bounds__(256) void rowptr_k(const int* __restrict__ dst,
                                                int* __restrict__ rp) {
    int t = blockIdx.x * blockDim.x + threadIdx.x;
    if (t > N_NODES) return;
    int lo = 0, hi = N_EDGES;
    while (lo < hi) {
        int mid = (lo + hi) >> 1;
        if (dst[mid] < t) lo = mid + 1; else hi = mid;
    }
    rp[t] = lo;
}

// ---------------- aniso conv: out[t, j*C+c] = sum_e k[j,e]*h[src[e],c] -----
// One thread per (node, in-channel); computes BOTH kernel outputs so each
// gathered value h[src[e], c] is loaded once.
template<int C, int IN_STRIDE, int OUT_STRIDE, int OUT_OFF>
__global__ __launch_bounds__(256) void conv_k(const float* __restrict__ hin,
                                              const float* __restrict__ kv,
                                              const int* __restrict__ src,
                                              const int* __restrict__ rp,
                                              float* __restrict__ hout) {
    int id = blockIdx.x * blockDim.x + threadIdx.x;
    if (id >= N_NODES * C) return;
    int t = id / C;
    int c = id - t * C;
    int e0 = rp[t], e1 = rp[t + 1];
    float a0 = 0.f, a1 = 0.f;
    for (int e = e0; e < e1; ++e) {
        int s = src[e];
        float v = hin[s * IN_STRIDE + c];
        a0 += kv[e] * v;
        a1 += kv[N_EDGES + e] * v;
    }
    hout[t * OUT_STRIDE + OUT_OFF + c]     = a0;
    hout[t * OUT_STRIDE + OUT_OFF + C + c] = a1;
}

// ---------------- lin0: h4 = relu(h3 @ W(36x72) + b) -----------------------
__global__ __launch_bounds__(256) void lin0_k(const float* __restrict__ h3,
                                              const float* __restrict__ w,
                                              const float* __restrict__ b,
                                              float* __restrict__ h4) {
    int id = blockIdx.x * blockDim.x + threadIdx.x;
    if (id >= N_NODES * 72) return;
    int t = id / 72;
    int o = id - t * 72;
    float acc = b[o];
#pragma unroll
    for (int i = 0; i < 36; ++i)
        acc += h3[t * 36 + i] * w[i * 72 + o];
    h4[t * 72 + o] = fmaxf(acc, 0.f);
}

// ---------------- fused MLP head + L2 normalize ----------------------------
// Block = 128 threads, processes 16 nodes. Stage h5 rows and hidden in LDS;
// register-block over the 16 nodes so W1/W2 stream once per 16 nodes.
#define MLP_M 16
__global__ __launch_bounds__(128) void mlp_k(const float* __restrict__ h5,
                                             const float* __restrict__ w1,
                                             const float* __restrict__ b1,
                                             const float* __restrict__ w2,
                                             const float* __restrict__ b2,
                                             float* __restrict__ out) {
    __shared__ float sh[MLP_M][144];
    __shared__ float shid[MLP_M][128];
    int block0 = blockIdx.x * MLP_M;
    int tid = threadIdx.x;

    // load 16 rows of h5 (16*144 floats, 128 threads)
    for (int i = tid; i < MLP_M * 144; i += 128) {
        int m = i / 144, ii = i - m * 144;
        sh[m][ii] = h5[(size_t)(block0 + m) * 144 + ii];
    }
    __syncthreads();

    // stage 1: hidden[m][o], o = tid (0..127)
    {
        float acc[MLP_M];
#pragma unroll
        for (int m = 0; m < MLP_M; ++m) acc[m] = b1[tid];
        for (int i = 0; i < 144; ++i) {
            float wv = w1[i * 128 + tid];
#pragma unroll
            for (int m = 0; m < MLP_M; ++m) acc[m] += sh[m][i] * wv;
        }
#pragma unroll
        for (int m = 0; m < MLP_M; ++m) shid[m][tid] = fmaxf(acc[m], 0.f);
    }
    __syncthreads();

    // stage 2: out[m][o], o = tid&63; wave0 -> nodes 0..7, wave1 -> 8..15
    {
        int o = tid & 63;
        int half = tid >> 6;
        const int MH = MLP_M / 2;
        float acc[MH];
#pragma unroll
        for (int m2 = 0; m2 < MH; ++m2) acc[m2] = b2[o];
        for (int j = 0; j < 128; ++j) {
            float wv = w2[j * 64 + o];
#pragma unroll
            for (int m2 = 0; m2 < MH; ++m2)
                acc[m2] += shid[half * MH + m2][j] * wv;
        }
        // L2 normalize each node's 64-vector (one wave holds one row)
#pragma unroll
        for (int m2 = 0; m2 < MH; ++m2) {
            float ss = acc[m2] * acc[m2];
#pragma unroll
            for (int d = 1; d < 64; d <<= 1) ss += __shfl_xor(ss, d);
            float nrm = sqrtf(ss);
            float scale = 1.f / fmaxf(nrm, 1e-12f);
            int t = block0 + half * MH + m2;
            out[(size_t)t * 64 + o] = acc[m2] * scale;
        }
    }
}

extern "C" void kernel_launch(void* const* d_in, const int* in_sizes, int n_in,
                              void* d_out, int out_size, void* d_ws, size_t ws_size,
                              hipStream_t stream) {
    const float* x   = (const float*)d_in[0];
    const float* kdd = (const float*)d_in[1];
    const float* kda = (const float*)d_in[2];
    const float* l0w = (const float*)d_in[3];
    const float* l0b = (const float*)d_in[4];
    const float* w1  = (const float*)d_in[5];
    const float* b1  = (const float*)d_in[6];
    const float* w2  = (const float*)d_in[7];
    const float* b2  = (const float*)d_in[8];
    const int*   src = (const int*)d_in[9];
    const int*   dst = (const int*)d_in[10];
    float* out = (float*)d_out;
    char* ws = (char*)d_ws;

    // workspace layout (bytes):
    //   rp   [0,          400004)
    //   h4   [1 MiB,      1 MiB + 28.8 MB)          N*72 f32
    //   hcat [30408704,   30408704 + 7.2 MB)        N*18 f32
    //   h3   [37748736,   37748736 + 14.4 MB)       N*36 f32
    //   h5   [30408704,   30408704 + 57.6 MB)       N*144 f32 (overlays dead hcat/h3)
    int*   rp   = (int*)ws;
    float* h4   = (float*)(ws + (1u << 20));
    float* hcat = (float*)(ws + 30408704u);
    float* h3   = (float*)(ws + 37748736u);
    float* h5   = (float*)(ws + 30408704u);

    rowptr_k<<<(N_NODES + 1 + 255) / 256, 256, 0, stream>>>(dst, rp);

    // DD phase: x[N,3] -> h1[N,6] (hcat cols 0:6) -> h2[N,12] (hcat cols 6:18)
    conv_k<3, 3, 18, 0><<<(N_NODES * 3 + 255) / 256, 256, 0, stream>>>(x, kdd, src, rp, hcat);
    conv_k<6, 18, 18, 6><<<(N_NODES * 6 + 255) / 256, 256, 0, stream>>>(hcat, kdd, src, rp, hcat);

    // DA phase
    conv_k<18, 18, 36, 0><<<(N_NODES * 18 + 255) / 256, 256, 0, stream>>>(hcat, kda, src, rp, h3);
    lin0_k<<<(N_NODES * 72 + 255) / 256, 256, 0, stream>>>(h3, l0w, l0b, h4);
    conv_k<72, 72, 144, 0><<<(N_NODES * 72 + 255) / 256, 256, 0, stream>>>(h4, kda, src, rp, h5);

    // MLP head + normalize
    mlp_k<<<N_NODES / MLP_M, 128, 0, stream>>>(h5, w1, b1, w2, b2, out);
}

// Round 2
// 371.593 us; speedup vs baseline: 1.3551x; 1.3551x over previous
//
#include <hip/hip_runtime.h>

#define N_NODES 100000
#define N_EDGES 1600000

// ---------------- row_ptr via binary search over sorted dst ----------------
__global__ __launch_bounds__(256) void rowptr_k(const int* __restrict__ dst,
                                                int* __restrict__ rp) {
    int t = blockIdx.x * blockDim.x + threadIdx.x;
    if (t > N_NODES) return;
    int lo = 0, hi = N_EDGES;
    while (lo < hi) {
        int mid = (lo + hi) >> 1;
        if (dst[mid] < t) lo = mid + 1; else hi = mid;
    }
    rp[t] = lo;
}

template<int VEC> struct VecT;
template<> struct VecT<1> { using T = float; };
template<> struct VecT<2> { using T = float2; };
template<> struct VecT<4> { using T = float4; };

// ---------------- aniso conv: out[t, j*C+c] = sum_e k[j,e]*h[src[e],c] -----
// One thread per (node, VEC-channel-group); computes BOTH kernel outputs.
// 4-edge software pipeline: 4 independent vector gathers in flight per lane.
template<int C, int VEC, int IN_STRIDE, int OUT_STRIDE, int OUT_OFF>
__global__ __launch_bounds__(256) void conv_k(const float* __restrict__ hin,
                                              const float* __restrict__ kv,
                                              const int* __restrict__ src,
                                              const int* __restrict__ rp,
                                              float* __restrict__ hout) {
    constexpr int G = C / VEC;
    using VT = typename VecT<VEC>::T;
    int id = blockIdx.x * blockDim.x + threadIdx.x;
    if (id >= N_NODES * G) return;
    int t = id / G;
    int g = id - t * G;
    int c0 = g * VEC;
    int e0 = rp[t], e1 = rp[t + 1];

    float a0[VEC], a1[VEC];
#pragma unroll
    for (int q = 0; q < VEC; ++q) { a0[q] = 0.f; a1[q] = 0.f; }

    int e = e0;
    for (; e + 4 <= e1; e += 4) {
        int s[4];
        float k0[4], k1[4];
#pragma unroll
        for (int u = 0; u < 4; ++u) s[u]  = src[e + u];
#pragma unroll
        for (int u = 0; u < 4; ++u) k0[u] = kv[e + u];
#pragma unroll
        for (int u = 0; u < 4; ++u) k1[u] = kv[N_EDGES + e + u];
        VT v[4];
#pragma unroll
        for (int u = 0; u < 4; ++u)
            v[u] = *reinterpret_cast<const VT*>(hin + (size_t)s[u] * IN_STRIDE + c0);
#pragma unroll
        for (int u = 0; u < 4; ++u) {
            const float* vf = reinterpret_cast<const float*>(&v[u]);
#pragma unroll
            for (int q = 0; q < VEC; ++q) {
                a0[q] += k0[u] * vf[q];
                a1[q] += k1[u] * vf[q];
            }
        }
    }
    for (; e < e1; ++e) {
        int s = src[e];
        float k0 = kv[e], k1 = kv[N_EDGES + e];
        VT v = *reinterpret_cast<const VT*>(hin + (size_t)s * IN_STRIDE + c0);
        const float* vf = reinterpret_cast<const float*>(&v);
#pragma unroll
        for (int q = 0; q < VEC; ++q) {
            a0[q] += k0 * vf[q];
            a1[q] += k1 * vf[q];
        }
    }

    VT r0, r1;
    float* r0f = reinterpret_cast<float*>(&r0);
    float* r1f = reinterpret_cast<float*>(&r1);
#pragma unroll
    for (int q = 0; q < VEC; ++q) { r0f[q] = a0[q]; r1f[q] = a1[q]; }
    *reinterpret_cast<VT*>(hout + (size_t)t * OUT_STRIDE + OUT_OFF + c0)     = r0;
    *reinterpret_cast<VT*>(hout + (size_t)t * OUT_STRIDE + OUT_OFF + C + c0) = r1;
}

// ---------------- lin0: h4 = relu(h3 @ W(36x72) + b) -----------------------
__global__ __launch_bounds__(256) void lin0_k(const float* __restrict__ h3,
                                              const float* __restrict__ w,
                                              const float* __restrict__ b,
                                              float* __restrict__ h4) {
    int id = blockIdx.x * blockDim.x + threadIdx.x;
    if (id >= N_NODES * 72) return;
    int t = id / 72;
    int o = id - t * 72;
    float acc = b[o];
#pragma unroll
    for (int i = 0; i < 36; ++i)
        acc += h3[t * 36 + i] * w[i * 72 + o];
    h4[t * 72 + o] = fmaxf(acc, 0.f);
}

// ---------------- fused MLP head + L2 normalize ----------------------------
#define MLP_M 16
__global__ __launch_bounds__(128) void mlp_k(const float* __restrict__ h5,
                                             const float* __restrict__ w1,
                                             const float* __restrict__ b1,
                                             const float* __restrict__ w2,
                                             const float* __restrict__ b2,
                                             float* __restrict__ out) {
    __shared__ float sh[MLP_M][144];
    __shared__ float shid[MLP_M][128];
    int block0 = blockIdx.x * MLP_M;
    int tid = threadIdx.x;

    for (int i = tid; i < MLP_M * 144; i += 128) {
        int m = i / 144, ii = i - m * 144;
        sh[m][ii] = h5[(size_t)(block0 + m) * 144 + ii];
    }
    __syncthreads();

    {
        float acc[MLP_M];
#pragma unroll
        for (int m = 0; m < MLP_M; ++m) acc[m] = b1[tid];
        for (int i = 0; i < 144; ++i) {
            float wv = w1[i * 128 + tid];
#pragma unroll
            for (int m = 0; m < MLP_M; ++m) acc[m] += sh[m][i] * wv;
        }
#pragma unroll
        for (int m = 0; m < MLP_M; ++m) shid[m][tid] = fmaxf(acc[m], 0.f);
    }
    __syncthreads();

    {
        int o = tid & 63;
        int half = tid >> 6;
        const int MH = MLP_M / 2;
        float acc[MH];
#pragma unroll
        for (int m2 = 0; m2 < MH; ++m2) acc[m2] = b2[o];
        for (int j = 0; j < 128; ++j) {
            float wv = w2[j * 64 + o];
#pragma unroll
            for (int m2 = 0; m2 < MH; ++m2)
                acc[m2] += shid[half * MH + m2][j] * wv;
        }
#pragma unroll
        for (int m2 = 0; m2 < MH; ++m2) {
            float ss = acc[m2] * acc[m2];
#pragma unroll
            for (int d = 1; d < 64; d <<= 1) ss += __shfl_xor(ss, d);
            float nrm = sqrtf(ss);
            float scale = 1.f / fmaxf(nrm, 1e-12f);
            int t = block0 + half * MH + m2;
            out[(size_t)t * 64 + o] = acc[m2] * scale;
        }
    }
}

extern "C" void kernel_launch(void* const* d_in, const int* in_sizes, int n_in,
                              void* d_out, int out_size, void* d_ws, size_t ws_size,
                              hipStream_t stream) {
    const float* x   = (const float*)d_in[0];
    const float* kdd = (const float*)d_in[1];
    const float* kda = (const float*)d_in[2];
    const float* l0w = (const float*)d_in[3];
    const float* l0b = (const float*)d_in[4];
    const float* w1  = (const float*)d_in[5];
    const float* b1  = (const float*)d_in[6];
    const float* w2  = (const float*)d_in[7];
    const float* b2  = (const float*)d_in[8];
    const int*   src = (const int*)d_in[9];
    const int*   dst = (const int*)d_in[10];
    float* out = (float*)d_out;
    char* ws = (char*)d_ws;

    // workspace layout (bytes):
    //   rp   [0,          400004)
    //   h4   [1 MiB,      1 MiB + 28.8 MB)          N*72 f32
    //   hcat [30408704,   30408704 + 7.2 MB)        N*18 f32
    //   h3   [37748736,   37748736 + 14.4 MB)       N*36 f32
    //   h5   [30408704,   30408704 + 57.6 MB)       N*144 f32 (overlays dead hcat/h3)
    int*   rp   = (int*)ws;
    float* h4   = (float*)(ws + (1u << 20));
    float* hcat = (float*)(ws + 30408704u);
    float* h3   = (float*)(ws + 37748736u);
    float* h5   = (float*)(ws + 30408704u);

    rowptr_k<<<(N_NODES + 1 + 255) / 256, 256, 0, stream>>>(dst, rp);

    // DD phase: x[N,3] -> h1[N,6] (hcat cols 0:6) -> h2[N,12] (hcat cols 6:18)
    conv_k<3, 1, 3, 18, 0><<<(N_NODES * 3 + 255) / 256, 256, 0, stream>>>(x, kdd, src, rp, hcat);
    conv_k<6, 2, 18, 18, 6><<<(N_NODES * 3 + 255) / 256, 256, 0, stream>>>(hcat, kdd, src, rp, hcat);

    // DA phase
    conv_k<18, 2, 18, 36, 0><<<(N_NODES * 9 + 255) / 256, 256, 0, stream>>>(hcat, kda, src, rp, h3);
    lin0_k<<<(N_NODES * 72 + 255) / 256, 256, 0, stream>>>(h3, l0w, l0b, h4);
    conv_k<72, 4, 72, 144, 0><<<(N_NODES * 18 + 255) / 256, 256, 0, stream>>>(h4, kda, src, rp, h5);

    // MLP head + normalize
    mlp_k<<<N_NODES / MLP_M, 128, 0, stream>>>(h5, w1, b1, w2, b2, out);
}

// Round 3
// 290.701 us; speedup vs baseline: 1.7322x; 1.2783x over previous
//
#include <hip/hip_runtime.h>

#define N_NODES 100000
#define N_EDGES 1600000

typedef __attribute__((ext_vector_type(8))) short short8;
typedef __attribute__((ext_vector_type(4))) float f32x4;
typedef __attribute__((ext_vector_type(4))) unsigned short ushort4v;
typedef __attribute__((ext_vector_type(8))) unsigned short ushort8v;

static __device__ inline unsigned short f2bf(float f) {
    union { float f; unsigned u; } v; v.f = f;
    unsigned r = v.u + 0x7FFF + ((v.u >> 16) & 1);   // round-to-nearest-even
    return (unsigned short)(r >> 16);
}

// ---------------- row_ptr via binary search over sorted dst ----------------
__global__ __launch_bounds__(256) void rowptr_k(const int* __restrict__ dst,
                                                int* __restrict__ rp) {
    int t = blockIdx.x * blockDim.x + threadIdx.x;
    if (t > N_NODES) return;
    int lo = 0, hi = N_EDGES;
    while (lo < hi) {
        int mid = (lo + hi) >> 1;
        if (dst[mid] < t) lo = mid + 1; else hi = mid;
    }
    rp[t] = lo;
}

// ---------------- weight prep: transpose + bf16 ----------------------------
// w1 [144,128] f32 -> w1t [128][160] bf16 (K-contig, zero pad k>=144)
// w2 [128,64]  f32 -> w2t [64][128]  bf16
__global__ __launch_bounds__(256) void prep_k(const float* __restrict__ w1,
                                              const float* __restrict__ w2,
                                              unsigned short* __restrict__ w1t,
                                              unsigned short* __restrict__ w2t) {
    int id = blockIdx.x * blockDim.x + threadIdx.x;
    if (id < 128 * 160) {
        int o = id / 160, k = id - o * 160;
        w1t[id] = (k < 144) ? f2bf(w1[k * 128 + o]) : (unsigned short)0;
    } else if (id < 128 * 160 + 64 * 128) {
        int j = id - 128 * 160;
        int o = j / 128, k = j - o * 128;
        w2t[j] = f2bf(w2[k * 64 + o]);
    }
}

template<int VEC> struct VecT;
template<> struct VecT<1> { using T = float; };
template<> struct VecT<2> { using T = float2; };
template<> struct VecT<4> { using T = float4; };

// ---------------- aniso conv (f32 out) -------------------------------------
template<int C, int VEC, int IN_STRIDE, int OUT_STRIDE, int OUT_OFF>
__global__ __launch_bounds__(256) void conv_k(const float* __restrict__ hin,
                                              const float* __restrict__ kv,
                                              const int* __restrict__ src,
                                              const int* __restrict__ rp,
                                              float* __restrict__ hout) {
    constexpr int G = C / VEC;
    using VT = typename VecT<VEC>::T;
    int id = blockIdx.x * blockDim.x + threadIdx.x;
    if (id >= N_NODES * G) return;
    int t = id / G;
    int g = id - t * G;
    int c0 = g * VEC;
    int e0 = rp[t], e1 = rp[t + 1];

    float a0[VEC], a1[VEC];
#pragma unroll
    for (int q = 0; q < VEC; ++q) { a0[q] = 0.f; a1[q] = 0.f; }

    int e = e0;
    for (; e + 4 <= e1; e += 4) {
        int s[4]; float k0[4], k1[4];
#pragma unroll
        for (int u = 0; u < 4; ++u) s[u]  = src[e + u];
#pragma unroll
        for (int u = 0; u < 4; ++u) k0[u] = kv[e + u];
#pragma unroll
        for (int u = 0; u < 4; ++u) k1[u] = kv[N_EDGES + e + u];
        VT v[4];
#pragma unroll
        for (int u = 0; u < 4; ++u)
            v[u] = *reinterpret_cast<const VT*>(hin + (size_t)s[u] * IN_STRIDE + c0);
#pragma unroll
        for (int u = 0; u < 4; ++u) {
            const float* vf = reinterpret_cast<const float*>(&v[u]);
#pragma unroll
            for (int q = 0; q < VEC; ++q) {
                a0[q] += k0[u] * vf[q];
                a1[q] += k1[u] * vf[q];
            }
        }
    }
    for (; e < e1; ++e) {
        int s = src[e];
        float k0 = kv[e], k1 = kv[N_EDGES + e];
        VT v = *reinterpret_cast<const VT*>(hin + (size_t)s * IN_STRIDE + c0);
        const float* vf = reinterpret_cast<const float*>(&v);
#pragma unroll
        for (int q = 0; q < VEC; ++q) { a0[q] += k0 * vf[q]; a1[q] += k1 * vf[q]; }
    }

    VT r0, r1;
    float* r0f = reinterpret_cast<float*>(&r0);
    float* r1f = reinterpret_cast<float*>(&r1);
#pragma unroll
    for (int q = 0; q < VEC; ++q) { r0f[q] = a0[q]; r1f[q] = a1[q]; }
    *reinterpret_cast<VT*>(hout + (size_t)t * OUT_STRIDE + OUT_OFF + c0)     = r0;
    *reinterpret_cast<VT*>(hout + (size_t)t * OUT_STRIDE + OUT_OFF + C + c0) = r1;
}

// ---------------- conv4: C=72, VEC=4, bf16 output [N][160] -----------------
__global__ __launch_bounds__(256) void conv4_k(const float* __restrict__ hin,
                                               const float* __restrict__ kv,
                                               const int* __restrict__ src,
                                               const int* __restrict__ rp,
                                               unsigned short* __restrict__ h5b) {
    int id = blockIdx.x * blockDim.x + threadIdx.x;
    if (id >= N_NODES * 18) return;
    int t = id / 18;
    int g = id - t * 18;
    int c0 = g * 4;
    int e0 = rp[t], e1 = rp[t + 1];

    float a0[4], a1[4];
#pragma unroll
    for (int q = 0; q < 4; ++q) { a0[q] = 0.f; a1[q] = 0.f; }

    int e = e0;
    for (; e + 4 <= e1; e += 4) {
        int s[4]; float k0[4], k1[4];
#pragma unroll
        for (int u = 0; u < 4; ++u) s[u]  = src[e + u];
#pragma unroll
        for (int u = 0; u < 4; ++u) k0[u] = kv[e + u];
#pragma unroll
        for (int u = 0; u < 4; ++u) k1[u] = kv[N_EDGES + e + u];
        float4 v[4];
#pragma unroll
        for (int u = 0; u < 4; ++u)
            v[u] = *reinterpret_cast<const float4*>(hin + (size_t)s[u] * 72 + c0);
#pragma unroll
        for (int u = 0; u < 4; ++u) {
            const float* vf = reinterpret_cast<const float*>(&v[u]);
#pragma unroll
            for (int q = 0; q < 4; ++q) { a0[q] += k0[u] * vf[q]; a1[q] += k1[u] * vf[q]; }
        }
    }
    for (; e < e1; ++e) {
        int s = src[e];
        float k0 = kv[e], k1 = kv[N_EDGES + e];
        float4 v = *reinterpret_cast<const float4*>(hin + (size_t)s * 72 + c0);
        const float* vf = reinterpret_cast<const float*>(&v);
#pragma unroll
        for (int q = 0; q < 4; ++q) { a0[q] += k0 * vf[q]; a1[q] += k1 * vf[q]; }
    }

    ushort4v r0, r1;
#pragma unroll
    for (int q = 0; q < 4; ++q) { r0[q] = f2bf(a0[q]); r1[q] = f2bf(a1[q]); }
    *reinterpret_cast<ushort4v*>(h5b + (size_t)t * 160 + c0)      = r0;
    *reinterpret_cast<ushort4v*>(h5b + (size_t)t * 160 + 72 + c0) = r1;
    if (g == 17) {   // zero the K-pad cols 144..159
        ushort8v z = {0,0,0,0,0,0,0,0};
        *reinterpret_cast<ushort8v*>(h5b + (size_t)t * 160 + 144) = z;
        *reinterpret_cast<ushort8v*>(h5b + (size_t)t * 160 + 152) = z;
    }
}

// ---------------- lin0: h4 = relu(h3 @ W(36x72) + b) -----------------------
__global__ __launch_bounds__(256) void lin0_k(const float* __restrict__ h3,
                                              const float* __restrict__ w,
                                              const float* __restrict__ b,
                                              float* __restrict__ h4) {
    int id = blockIdx.x * blockDim.x + threadIdx.x;
    if (id >= N_NODES * 72) return;
    int t = id / 72;
    int o = id - t * 72;
    float acc = b[o];
#pragma unroll
    for (int i = 0; i < 36; ++i)
        acc += h3[t * 36 + i] * w[i * 72 + o];
    h4[t * 72 + o] = fmaxf(acc, 0.f);
}

// ---------------- MFMA MLP head + L2 normalize -----------------------------
// Block = 256 thr (4 waves), 64 nodes/block; wave w owns nodes [w*16, w*16+16).
// Stage1: hidden[64,128] = relu(h5b[64,160]@w1t + b1)  (5 K-steps, 8 N-tiles)
// Stage2: out = norm(hidden@w2t + b2)                  (4 K-steps, 4 N-tiles)
#define HSTRIDE 136
__global__ __launch_bounds__(256) void mlp_k(const unsigned short* __restrict__ h5b,
                                             const unsigned short* __restrict__ w1t,
                                             const float* __restrict__ b1,
                                             const unsigned short* __restrict__ w2t,
                                             const float* __restrict__ b2,
                                             float* __restrict__ out) {
    __shared__ unsigned short sh[64 * HSTRIDE];
    int tid = threadIdx.x;
    int w = tid >> 6;
    int lane = tid & 63;
    int lr = lane & 15;        // row/col within 16-tile
    int kg = lane >> 4;        // k-group
    int row_base = blockIdx.x * 64 + w * 16;

    // ---- stage 1 ----
    f32x4 acc[8];
#pragma unroll
    for (int n = 0; n < 8; ++n) acc[n] = (f32x4){0.f, 0.f, 0.f, 0.f};

    const unsigned short* arow = h5b + (size_t)(row_base + lr) * 160 + kg * 8;
#pragma unroll
    for (int ks = 0; ks < 5; ++ks) {
        short8 a = *reinterpret_cast<const short8*>(arow + ks * 32);
#pragma unroll
        for (int n = 0; n < 8; ++n) {
            short8 b = *reinterpret_cast<const short8*>(w1t + (n * 16 + lr) * 160 + ks * 32 + kg * 8);
            acc[n] = __builtin_amdgcn_mfma_f32_16x16x32_bf16(a, b, acc[n], 0, 0, 0);
        }
    }
    // bias + relu -> LDS (bf16), row = w*16 + kg*4 + q, col = n*16 + lr
#pragma unroll
    for (int n = 0; n < 8; ++n) {
        float bv = b1[n * 16 + lr];
#pragma unroll
        for (int q = 0; q < 4; ++q) {
            float hv = fmaxf(acc[n][q] + bv, 0.f);
            sh[(w * 16 + kg * 4 + q) * HSTRIDE + n * 16 + lr] = f2bf(hv);
        }
    }
    __syncthreads();

    // ---- stage 2 ----
    f32x4 acc2[4];
#pragma unroll
    for (int n = 0; n < 4; ++n) acc2[n] = (f32x4){0.f, 0.f, 0.f, 0.f};
#pragma unroll
    for (int ks = 0; ks < 4; ++ks) {
        short8 a = *reinterpret_cast<const short8*>(sh + (w * 16 + lr) * HSTRIDE + ks * 32 + kg * 8);
#pragma unroll
        for (int n = 0; n < 4; ++n) {
            short8 b = *reinterpret_cast<const short8*>(w2t + (n * 16 + lr) * 128 + ks * 32 + kg * 8);
            acc2[n] = __builtin_amdgcn_mfma_f32_16x16x32_bf16(a, b, acc2[n], 0, 0, 0);
        }
    }

    // bias, then per-node L2 norm. Node r = row_base + kg*4 + q; its 64 values
    // live in lanes {kg*16..kg*16+15} reg q across the 4 N-tiles.
    float v[4][4];
    float ss[4];
#pragma unroll
    for (int q = 0; q < 4; ++q) ss[q] = 0.f;
#pragma unroll
    for (int n = 0; n < 4; ++n) {
        float bv = b2[n * 16 + lr];
#pragma unroll
        for (int q = 0; q < 4; ++q) {
            float x = acc2[n][q] + bv;
            v[n][q] = x;
            ss[q] += x * x;
        }
    }
#pragma unroll
    for (int q = 0; q < 4; ++q) {
#pragma unroll
        for (int d = 1; d < 16; d <<= 1) ss[q] += __shfl_xor(ss[q], d);
    }
#pragma unroll
    for (int q = 0; q < 4; ++q) {
        int node = row_base + kg * 4 + q;
        if (node < N_NODES) {
            float scale = 1.f / fmaxf(sqrtf(ss[q]), 1e-12f);
#pragma unroll
            for (int n = 0; n < 4; ++n)
                out[(size_t)node * 64 + n * 16 + lr] = v[n][q] * scale;
        }
    }
}

extern "C" void kernel_launch(void* const* d_in, const int* in_sizes, int n_in,
                              void* d_out, int out_size, void* d_ws, size_t ws_size,
                              hipStream_t stream) {
    const float* x   = (const float*)d_in[0];
    const float* kdd = (const float*)d_in[1];
    const float* kda = (const float*)d_in[2];
    const float* l0w = (const float*)d_in[3];
    const float* l0b = (const float*)d_in[4];
    const float* w1  = (const float*)d_in[5];
    const float* b1  = (const float*)d_in[6];
    const float* w2  = (const float*)d_in[7];
    const float* b2  = (const float*)d_in[8];
    const int*   src = (const int*)d_in[9];
    const int*   dst = (const int*)d_in[10];
    float* out = (float*)d_out;
    char* ws = (char*)d_ws;

    // workspace layout (bytes):
    //   rp    [0, 400004)
    //   w1t   [450560, +40960)      bf16 128x160
    //   w2t   [491520, +16384)      bf16 64x128
    //   h4    [1 MiB, +28.8 MB)     f32 N*72
    //   hcat  [30408704, +7.2 MB)   f32 N*18
    //   h3    [37748736, +14.4 MB)  f32 N*36
    //   h5b   [30408704, +32.02 MB) bf16 100032x160 (overlays dead hcat/h3)
    int*   rp   = (int*)ws;
    unsigned short* w1t = (unsigned short*)(ws + 450560u);
    unsigned short* w2t = (unsigned short*)(ws + 491520u);
    float* h4   = (float*)(ws + (1u << 20));
    float* hcat = (float*)(ws + 30408704u);
    float* h3   = (float*)(ws + 37748736u);
    unsigned short* h5b = (unsigned short*)(ws + 30408704u);

    rowptr_k<<<(N_NODES + 1 + 255) / 256, 256, 0, stream>>>(dst, rp);
    prep_k<<<(128 * 160 + 64 * 128 + 255) / 256, 256, 0, stream>>>(w1, w2, w1t, w2t);

    // DD phase
    conv_k<3, 1, 3, 18, 0><<<(N_NODES * 3 + 255) / 256, 256, 0, stream>>>(x, kdd, src, rp, hcat);
    conv_k<6, 2, 18, 18, 6><<<(N_NODES * 3 + 255) / 256, 256, 0, stream>>>(hcat, kdd, src, rp, hcat);

    // DA phase
    conv_k<18, 2, 18, 36, 0><<<(N_NODES * 9 + 255) / 256, 256, 0, stream>>>(hcat, kda, src, rp, h3);
    lin0_k<<<(N_NODES * 72 + 255) / 256, 256, 0, stream>>>(h3, l0w, l0b, h4);
    conv4_k<<<(N_NODES * 18 + 255) / 256, 256, 0, stream>>>(h4, kda, src, rp, h5b);

    // MFMA MLP head + normalize
    mlp_k<<<(N_NODES + 63) / 64, 256, 0, stream>>>(h5b, w1t, b1, w2t, b2, out);
}

// Round 4
// 245.774 us; speedup vs baseline: 2.0489x; 1.1828x over previous
//
#include <hip/hip_runtime.h>

#define N_NODES 100000
#define N_EDGES 1600000

typedef __attribute__((ext_vector_type(8))) short short8;
typedef __attribute__((ext_vector_type(4))) float f32x4;
typedef __attribute__((ext_vector_type(2))) unsigned short ushort2v;
typedef __attribute__((ext_vector_type(4))) unsigned short ushort4v;
typedef __attribute__((ext_vector_type(8))) unsigned short ushort8v;

static __device__ inline unsigned short f2bf(float f) {
    union { float f; unsigned u; } v; v.f = f;
    unsigned r = v.u + 0x7FFF + ((v.u >> 16) & 1);   // round-to-nearest-even
    return (unsigned short)(r >> 16);
}
static __device__ inline float bf2f(unsigned short u) {
    union { unsigned u; float f; } v; v.u = ((unsigned)u) << 16;
    return v.f;
}

// ---------------- row_ptr via binary search over sorted dst ----------------
__global__ __launch_bounds__(256) void rowptr_k(const int* __restrict__ dst,
                                                int* __restrict__ rp) {
    int t = blockIdx.x * blockDim.x + threadIdx.x;
    if (t > N_NODES) return;
    int lo = 0, hi = N_EDGES;
    while (lo < hi) {
        int mid = (lo + hi) >> 1;
        if (dst[mid] < t) lo = mid + 1; else hi = mid;
    }
    rp[t] = lo;
}

// ---------------- weight prep: transpose + bf16 ----------------------------
__global__ __launch_bounds__(256) void prep_k(const float* __restrict__ w1,
                                              const float* __restrict__ w2,
                                              unsigned short* __restrict__ w1t,
                                              unsigned short* __restrict__ w2t) {
    int id = blockIdx.x * blockDim.x + threadIdx.x;
    if (id < 128 * 160) {
        int o = id / 160, k = id - o * 160;
        w1t[id] = (k < 144) ? f2bf(w1[k * 128 + o]) : (unsigned short)0;
    } else if (id < 128 * 160 + 64 * 128) {
        int j = id - 128 * 160;
        int o = j / 128, k = j - o * 128;
        w2t[j] = f2bf(w2[k * 64 + o]);
    }
}

template<int VEC> struct VecU;
template<> struct VecU<1> { using T = unsigned short; };
template<> struct VecU<2> { using T = ushort2v; };
template<> struct VecU<4> { using T = ushort4v; };
template<> struct VecU<8> { using T = ushort8v; };

// ---------------- conv1: f32 in [N][3] -> bf16 out (stride OUT_STRIDE) -----
template<int OUT_STRIDE>
__global__ __launch_bounds__(256) void conv1_k(const float* __restrict__ hin,
                                               const float* __restrict__ kv,
                                               const int* __restrict__ src,
                                               const int* __restrict__ rp,
                                               unsigned short* __restrict__ hout) {
    int id = blockIdx.x * blockDim.x + threadIdx.x;
    if (id >= N_NODES * 3) return;
    int t = id / 3;
    int c = id - t * 3;
    int e0 = rp[t], e1 = rp[t + 1];
    float a0 = 0.f, a1 = 0.f;
    int e = e0;
    for (; e + 4 <= e1; e += 4) {
        int s[4]; float k0[4], k1[4], v[4];
#pragma unroll
        for (int u = 0; u < 4; ++u) s[u]  = src[e + u];
#pragma unroll
        for (int u = 0; u < 4; ++u) k0[u] = kv[e + u];
#pragma unroll
        for (int u = 0; u < 4; ++u) k1[u] = kv[N_EDGES + e + u];
#pragma unroll
        for (int u = 0; u < 4; ++u) v[u]  = hin[(size_t)s[u] * 3 + c];
#pragma unroll
        for (int u = 0; u < 4; ++u) { a0 += k0[u] * v[u]; a1 += k1[u] * v[u]; }
    }
    for (; e < e1; ++e) {
        int s = src[e];
        float v = hin[(size_t)s * 3 + c];
        a0 += kv[e] * v;
        a1 += kv[N_EDGES + e] * v;
    }
    hout[(size_t)t * OUT_STRIDE + c]     = f2bf(a0);
    hout[(size_t)t * OUT_STRIDE + 3 + c] = f2bf(a1);
}

// ---------------- bf16 aniso conv ------------------------------------------
// out[t, c] and out[t, C+c]; input bf16, accumulate f32, output bf16.
template<int C, int VEC, int IN_STRIDE, int OUT_STRIDE, int OUT_OFF, bool PAD160>
__global__ __launch_bounds__(256) void convb_k(const unsigned short* __restrict__ hin,
                                               const float* __restrict__ kv,
                                               const int* __restrict__ src,
                                               const int* __restrict__ rp,
                                               unsigned short* __restrict__ hout) {
    constexpr int G = C / VEC;
    using VT = typename VecU<VEC>::T;
    int id = blockIdx.x * blockDim.x + threadIdx.x;
    if (id >= N_NODES * G) return;
    int t = id / G;
    int g = id - t * G;
    int c0 = g * VEC;
    int e0 = rp[t], e1 = rp[t + 1];

    float a0[VEC], a1[VEC];
#pragma unroll
    for (int q = 0; q < VEC; ++q) { a0[q] = 0.f; a1[q] = 0.f; }

    int e = e0;
    for (; e + 4 <= e1; e += 4) {
        int s[4]; float k0[4], k1[4];
#pragma unroll
        for (int u = 0; u < 4; ++u) s[u]  = src[e + u];
#pragma unroll
        for (int u = 0; u < 4; ++u) k0[u] = kv[e + u];
#pragma unroll
        for (int u = 0; u < 4; ++u) k1[u] = kv[N_EDGES + e + u];
        VT v[4];
#pragma unroll
        for (int u = 0; u < 4; ++u)
            v[u] = *reinterpret_cast<const VT*>(hin + (size_t)s[u] * IN_STRIDE + c0);
#pragma unroll
        for (int u = 0; u < 4; ++u) {
            const unsigned short* vf = reinterpret_cast<const unsigned short*>(&v[u]);
#pragma unroll
            for (int q = 0; q < VEC; ++q) {
                float x = bf2f(vf[q]);
                a0[q] += k0[u] * x;
                a1[q] += k1[u] * x;
            }
        }
    }
    for (; e < e1; ++e) {
        int s = src[e];
        float k0 = kv[e], k1 = kv[N_EDGES + e];
        VT v = *reinterpret_cast<const VT*>(hin + (size_t)s * IN_STRIDE + c0);
        const unsigned short* vf = reinterpret_cast<const unsigned short*>(&v);
#pragma unroll
        for (int q = 0; q < VEC; ++q) {
            float x = bf2f(vf[q]);
            a0[q] += k0 * x;
            a1[q] += k1 * x;
        }
    }

    VT r0, r1;
    unsigned short* r0f = reinterpret_cast<unsigned short*>(&r0);
    unsigned short* r1f = reinterpret_cast<unsigned short*>(&r1);
#pragma unroll
    for (int q = 0; q < VEC; ++q) { r0f[q] = f2bf(a0[q]); r1f[q] = f2bf(a1[q]); }
    *reinterpret_cast<VT*>(hout + (size_t)t * OUT_STRIDE + OUT_OFF + c0)     = r0;
    *reinterpret_cast<VT*>(hout + (size_t)t * OUT_STRIDE + OUT_OFF + C + c0) = r1;

    if (PAD160 && g == G - 1) {   // zero K-pad cols 144..159 (for MFMA)
        ushort8v z = {0, 0, 0, 0, 0, 0, 0, 0};
        *reinterpret_cast<ushort8v*>(hout + (size_t)t * OUT_STRIDE + 144) = z;
        *reinterpret_cast<ushort8v*>(hout + (size_t)t * OUT_STRIDE + 152) = z;
    }
}

// ---------------- lin0: h4b = relu(h3b @ W(36x72) + b), bf16 in/out --------
__global__ __launch_bounds__(256) void lin0_k(const unsigned short* __restrict__ h3b,
                                              const float* __restrict__ w,
                                              const float* __restrict__ b,
                                              unsigned short* __restrict__ h4b) {
    int id = blockIdx.x * blockDim.x + threadIdx.x;
    if (id >= N_NODES * 36) return;
    int t = id / 36;
    int op = id - t * 36;
    int o0 = op * 2;

    float row[36];
    const ushort4v* r4 = reinterpret_cast<const ushort4v*>(h3b + (size_t)t * 36);
#pragma unroll
    for (int i = 0; i < 9; ++i) {
        ushort4v u = r4[i];
#pragma unroll
        for (int q = 0; q < 4; ++q) row[i * 4 + q] = bf2f(u[q]);
    }
    float a0 = b[o0], a1 = b[o0 + 1];
#pragma unroll
    for (int i = 0; i < 36; ++i) {
        a0 += row[i] * w[i * 72 + o0];
        a1 += row[i] * w[i * 72 + o0 + 1];
    }
    ushort2v r;
    r[0] = f2bf(fmaxf(a0, 0.f));
    r[1] = f2bf(fmaxf(a1, 0.f));
    *reinterpret_cast<ushort2v*>(h4b + (size_t)t * 72 + o0) = r;
}

// ---------------- MFMA MLP head + L2 normalize -----------------------------
#define HSTRIDE 136
__global__ __launch_bounds__(256) void mlp_k(const unsigned short* __restrict__ h5b,
                                             const unsigned short* __restrict__ w1t,
                                             const float* __restrict__ b1,
                                             const unsigned short* __restrict__ w2t,
                                             const float* __restrict__ b2,
                                             float* __restrict__ out) {
    __shared__ unsigned short sh[64 * HSTRIDE];
    int tid = threadIdx.x;
    int w = tid >> 6;
    int lane = tid & 63;
    int lr = lane & 15;
    int kg = lane >> 4;
    int row_base = blockIdx.x * 64 + w * 16;

    // ---- stage 1 ----
    f32x4 acc[8];
#pragma unroll
    for (int n = 0; n < 8; ++n) acc[n] = (f32x4){0.f, 0.f, 0.f, 0.f};

    const unsigned short* arow = h5b + (size_t)(row_base + lr) * 160 + kg * 8;
#pragma unroll
    for (int ks = 0; ks < 5; ++ks) {
        short8 a = *reinterpret_cast<const short8*>(arow + ks * 32);
#pragma unroll
        for (int n = 0; n < 8; ++n) {
            short8 b = *reinterpret_cast<const short8*>(w1t + (n * 16 + lr) * 160 + ks * 32 + kg * 8);
            acc[n] = __builtin_amdgcn_mfma_f32_16x16x32_bf16(a, b, acc[n], 0, 0, 0);
        }
    }
#pragma unroll
    for (int n = 0; n < 8; ++n) {
        float bv = b1[n * 16 + lr];
#pragma unroll
        for (int q = 0; q < 4; ++q) {
            float hv = fmaxf(acc[n][q] + bv, 0.f);
            sh[(w * 16 + kg * 4 + q) * HSTRIDE + n * 16 + lr] = f2bf(hv);
        }
    }
    __syncthreads();

    // ---- stage 2 ----
    f32x4 acc2[4];
#pragma unroll
    for (int n = 0; n < 4; ++n) acc2[n] = (f32x4){0.f, 0.f, 0.f, 0.f};
#pragma unroll
    for (int ks = 0; ks < 4; ++ks) {
        short8 a = *reinterpret_cast<const short8*>(sh + (w * 16 + lr) * HSTRIDE + ks * 32 + kg * 8);
#pragma unroll
        for (int n = 0; n < 4; ++n) {
            short8 b = *reinterpret_cast<const short8*>(w2t + (n * 16 + lr) * 128 + ks * 32 + kg * 8);
            acc2[n] = __builtin_amdgcn_mfma_f32_16x16x32_bf16(a, b, acc2[n], 0, 0, 0);
        }
    }

    float v[4][4];
    float ss[4];
#pragma unroll
    for (int q = 0; q < 4; ++q) ss[q] = 0.f;
#pragma unroll
    for (int n = 0; n < 4; ++n) {
        float bv = b2[n * 16 + lr];
#pragma unroll
        for (int q = 0; q < 4; ++q) {
            float x = acc2[n][q] + bv;
            v[n][q] = x;
            ss[q] += x * x;
        }
    }
#pragma unroll
    for (int q = 0; q < 4; ++q) {
#pragma unroll
        for (int d = 1; d < 16; d <<= 1) ss[q] += __shfl_xor(ss[q], d);
    }
#pragma unroll
    for (int q = 0; q < 4; ++q) {
        int node = row_base + kg * 4 + q;
        if (node < N_NODES) {
            float scale = 1.f / fmaxf(sqrtf(ss[q]), 1e-12f);
#pragma unroll
            for (int n = 0; n < 4; ++n)
                out[(size_t)node * 64 + n * 16 + lr] = v[n][q] * scale;
        }
    }
}

extern "C" void kernel_launch(void* const* d_in, const int* in_sizes, int n_in,
                              void* d_out, int out_size, void* d_ws, size_t ws_size,
                              hipStream_t stream) {
    const float* x   = (const float*)d_in[0];
    const float* kdd = (const float*)d_in[1];
    const float* kda = (const float*)d_in[2];
    const float* l0w = (const float*)d_in[3];
    const float* l0b = (const float*)d_in[4];
    const float* w1  = (const float*)d_in[5];
    const float* b1  = (const float*)d_in[6];
    const float* w2  = (const float*)d_in[7];
    const float* b2  = (const float*)d_in[8];
    const int*   src = (const int*)d_in[9];
    const int*   dst = (const int*)d_in[10];
    float* out = (float*)d_out;
    char* ws = (char*)d_ws;

    // workspace layout (bytes):
    //   rp    [0, +400004)
    //   w1t   [450560, +40960)       bf16 128x160
    //   w2t   [491520, +16384)       bf16 64x128
    //   hcb   [1 MiB, +4.0 MB)       bf16 N*20   (h1 cols 0:6, h2 cols 6:18)
    //   h3b   [6 MiB, +7.2 MB)       bf16 N*36
    //   h4b   [14 MiB, +14.4 MB)     bf16 N*72
    //   h5b   [30 MiB, +32.01 MB)    bf16 100032*160
    int*   rp  = (int*)ws;
    unsigned short* w1t = (unsigned short*)(ws + 450560u);
    unsigned short* w2t = (unsigned short*)(ws + 491520u);
    unsigned short* hcb = (unsigned short*)(ws + (1u << 20));
    unsigned short* h3b = (unsigned short*)(ws + (6u << 20));
    unsigned short* h4b = (unsigned short*)(ws + (14u << 20));
    unsigned short* h5b = (unsigned short*)(ws + (30u << 20));

    rowptr_k<<<(N_NODES + 1 + 255) / 256, 256, 0, stream>>>(dst, rp);
    prep_k<<<(128 * 160 + 64 * 128 + 255) / 256, 256, 0, stream>>>(w1, w2, w1t, w2t);

    // DD phase: x[N,3] -> h1 (hcb cols 0:6) -> h2 (hcb cols 6:18)
    conv1_k<20><<<(N_NODES * 3 + 255) / 256, 256, 0, stream>>>(x, kdd, src, rp, hcb);
    convb_k<6, 2, 20, 20, 6, false><<<(N_NODES * 3 + 255) / 256, 256, 0, stream>>>(hcb, kdd, src, rp, hcb);

    // DA phase
    convb_k<18, 2, 20, 36, 0, false><<<(N_NODES * 9 + 255) / 256, 256, 0, stream>>>(hcb, kda, src, rp, h3b);
    lin0_k<<<(N_NODES * 36 + 255) / 256, 256, 0, stream>>>(h3b, l0w, l0b, h4b);
    convb_k<72, 8, 72, 160, 0, true><<<(N_NODES * 9 + 255) / 256, 256, 0, stream>>>(h4b, kda, src, rp, h5b);

    // MFMA MLP head + normalize
    mlp_k<<<(N_NODES + 63) / 64, 256, 0, stream>>>(h5b, w1t, b1, w2t, b2, out);
}

// Round 5
// 197.538 us; speedup vs baseline: 2.5492x; 1.2442x over previous
//
#include <hip/hip_runtime.h>

#define N_NODES 100000
#define N_EDGES 1600000

typedef __attribute__((ext_vector_type(8))) short short8;
typedef __attribute__((ext_vector_type(4))) float f32x4;
typedef __attribute__((ext_vector_type(2))) unsigned short ushort2v;
typedef __attribute__((ext_vector_type(4))) unsigned short ushort4v;
typedef __attribute__((ext_vector_type(8))) unsigned short ushort8v;

static __device__ inline unsigned short f2bf(float f) {
    union { float f; unsigned u; } v; v.f = f;
    unsigned r = v.u + 0x7FFF + ((v.u >> 16) & 1);   // round-to-nearest-even
    return (unsigned short)(r >> 16);
}
static __device__ inline float bf2f(unsigned short u) {
    union { unsigned u; float f; } v; v.u = ((unsigned)u) << 16;
    return v.f;
}

// ---------------- row_ptr via binary search over sorted dst ----------------
__global__ __launch_bounds__(256) void rowptr_k(const int* __restrict__ dst,
                                                int* __restrict__ rp) {
    int t = blockIdx.x * blockDim.x + threadIdx.x;
    if (t > N_NODES) return;
    int lo = 0, hi = N_EDGES;
    while (lo < hi) {
        int mid = (lo + hi) >> 1;
        if (dst[mid] < t) lo = mid + 1; else hi = mid;
    }
    rp[t] = lo;
}

// ---------------- weight prep: transpose + bf16 ----------------------------
// w1 [144,128] -> w1t [128][160]; w2 [128,64] -> w2t [64][128];
// l0w [36,72]  -> w0t [80][64]   (all K-contig, zero-padded)
__global__ __launch_bounds__(256) void prep_k(const float* __restrict__ w1,
                                              const float* __restrict__ w2,
                                              const float* __restrict__ l0w,
                                              unsigned short* __restrict__ w1t,
                                              unsigned short* __restrict__ w2t,
                                              unsigned short* __restrict__ w0t) {
    int id = blockIdx.x * blockDim.x + threadIdx.x;
    if (id < 128 * 160) {
        int o = id / 160, k = id - o * 160;
        w1t[id] = (k < 144) ? f2bf(w1[k * 128 + o]) : (unsigned short)0;
    } else if (id < 128 * 160 + 64 * 128) {
        int j = id - 128 * 160;
        int o = j / 128, k = j - o * 128;
        w2t[j] = f2bf(w2[k * 64 + o]);
    } else if (id < 128 * 160 + 64 * 128 + 80 * 64) {
        int j = id - 128 * 160 - 64 * 128;
        int o = j / 64, k = j - o * 64;
        w0t[j] = (o < 72 && k < 36) ? f2bf(l0w[k * 72 + o]) : (unsigned short)0;
    }
}

template<int VEC> struct VecU;
template<> struct VecU<1> { using T = unsigned short; };
template<> struct VecU<2> { using T = ushort2v; };
template<> struct VecU<4> { using T = ushort4v; };
template<> struct VecU<8> { using T = ushort8v; };

// ---------------- conv1: f32 in [N][3] -> bf16 out (stride OUT_STRIDE) -----
template<int OUT_STRIDE>
__global__ __launch_bounds__(256) void conv1_k(const float* __restrict__ hin,
                                               const float* __restrict__ kv,
                                               const int* __restrict__ src,
                                               const int* __restrict__ rp,
                                               unsigned short* __restrict__ hout) {
    int id = blockIdx.x * blockDim.x + threadIdx.x;
    if (id >= N_NODES * 3) return;
    int t = id / 3;
    int c = id - t * 3;
    int e0 = rp[t], e1 = rp[t + 1];
    float a0 = 0.f, a1 = 0.f;
    int e = e0;
    for (; e + 4 <= e1; e += 4) {
        int s[4]; float k0[4], k1[4], v[4];
#pragma unroll
        for (int u = 0; u < 4; ++u) s[u]  = src[e + u];
#pragma unroll
        for (int u = 0; u < 4; ++u) k0[u] = kv[e + u];
#pragma unroll
        for (int u = 0; u < 4; ++u) k1[u] = kv[N_EDGES + e + u];
#pragma unroll
        for (int u = 0; u < 4; ++u) v[u]  = hin[(size_t)s[u] * 3 + c];
#pragma unroll
        for (int u = 0; u < 4; ++u) { a0 += k0[u] * v[u]; a1 += k1[u] * v[u]; }
    }
    for (; e < e1; ++e) {
        int s = src[e];
        float v = hin[(size_t)s * 3 + c];
        a0 += kv[e] * v;
        a1 += kv[N_EDGES + e] * v;
    }
    hout[(size_t)t * OUT_STRIDE + c]     = f2bf(a0);
    hout[(size_t)t * OUT_STRIDE + 3 + c] = f2bf(a1);
}

// ---------------- bf16 aniso conv ------------------------------------------
template<int C, int VEC, int IN_STRIDE, int OUT_STRIDE, int OUT_OFF,
         int PAD_FROM, int PAD_TO>
__global__ __launch_bounds__(256) void convb_k(const unsigned short* __restrict__ hin,
                                               const float* __restrict__ kv,
                                               const int* __restrict__ src,
                                               const int* __restrict__ rp,
                                               unsigned short* __restrict__ hout) {
    constexpr int G = C / VEC;
    using VT = typename VecU<VEC>::T;
    int id = blockIdx.x * blockDim.x + threadIdx.x;
    if (id >= N_NODES * G) return;
    int t = id / G;
    int g = id - t * G;
    int c0 = g * VEC;
    int e0 = rp[t], e1 = rp[t + 1];

    float a0[VEC], a1[VEC];
#pragma unroll
    for (int q = 0; q < VEC; ++q) { a0[q] = 0.f; a1[q] = 0.f; }

    int e = e0;
    for (; e + 4 <= e1; e += 4) {
        int s[4]; float k0[4], k1[4];
#pragma unroll
        for (int u = 0; u < 4; ++u) s[u]  = src[e + u];
#pragma unroll
        for (int u = 0; u < 4; ++u) k0[u] = kv[e + u];
#pragma unroll
        for (int u = 0; u < 4; ++u) k1[u] = kv[N_EDGES + e + u];
        VT v[4];
#pragma unroll
        for (int u = 0; u < 4; ++u)
            v[u] = *reinterpret_cast<const VT*>(hin + (size_t)s[u] * IN_STRIDE + c0);
#pragma unroll
        for (int u = 0; u < 4; ++u) {
            const unsigned short* vf = reinterpret_cast<const unsigned short*>(&v[u]);
#pragma unroll
            for (int q = 0; q < VEC; ++q) {
                float x = bf2f(vf[q]);
                a0[q] += k0[u] * x;
                a1[q] += k1[u] * x;
            }
        }
    }
    for (; e < e1; ++e) {
        int s = src[e];
        float k0 = kv[e], k1 = kv[N_EDGES + e];
        VT v = *reinterpret_cast<const VT*>(hin + (size_t)s * IN_STRIDE + c0);
        const unsigned short* vf = reinterpret_cast<const unsigned short*>(&v);
#pragma unroll
        for (int q = 0; q < VEC; ++q) {
            float x = bf2f(vf[q]);
            a0[q] += k0 * x;
            a1[q] += k1 * x;
        }
    }

    VT r0, r1;
    unsigned short* r0f = reinterpret_cast<unsigned short*>(&r0);
    unsigned short* r1f = reinterpret_cast<unsigned short*>(&r1);
#pragma unroll
    for (int q = 0; q < VEC; ++q) { r0f[q] = f2bf(a0[q]); r1f[q] = f2bf(a1[q]); }
    *reinterpret_cast<VT*>(hout + (size_t)t * OUT_STRIDE + OUT_OFF + c0)     = r0;
    *reinterpret_cast<VT*>(hout + (size_t)t * OUT_STRIDE + OUT_OFF + C + c0) = r1;

    if constexpr (PAD_TO > PAD_FROM) {
        if (g == G - 1) {
            ushort4v z = {0, 0, 0, 0};
#pragma unroll
            for (int j = PAD_FROM; j < PAD_TO; j += 4)
                *reinterpret_cast<ushort4v*>(hout + (size_t)t * OUT_STRIDE + j) = z;
        }
    }
}

// ---------------- lin0 via MFMA: h4b = relu(h3b[N][64] @ w0t + b0) ---------
// Block = 256 thr (4 waves), 64 nodes/block; wave w owns nodes [w*16, +16).
// 2 K-steps x 5 N-tiles (80 padded outputs, 72 real).
__global__ __launch_bounds__(256) void lin0m_k(const unsigned short* __restrict__ h3b,
                                               const unsigned short* __restrict__ w0t,
                                               const float* __restrict__ b0,
                                               unsigned short* __restrict__ h4b) {
    int tid = threadIdx.x;
    int w = tid >> 6;
    int lane = tid & 63;
    int lr = lane & 15;
    int kg = lane >> 4;
    int row_base = blockIdx.x * 64 + w * 16;

    f32x4 acc[5];
#pragma unroll
    for (int n = 0; n < 5; ++n) acc[n] = (f32x4){0.f, 0.f, 0.f, 0.f};

    const unsigned short* arow = h3b + (size_t)(row_base + lr) * 64 + kg * 8;
#pragma unroll
    for (int ks = 0; ks < 2; ++ks) {
        short8 a = *reinterpret_cast<const short8*>(arow + ks * 32);
#pragma unroll
        for (int n = 0; n < 5; ++n) {
            short8 b = *reinterpret_cast<const short8*>(w0t + (n * 16 + lr) * 64 + ks * 32 + kg * 8);
            acc[n] = __builtin_amdgcn_mfma_f32_16x16x32_bf16(a, b, acc[n], 0, 0, 0);
        }
    }
#pragma unroll
    for (int n = 0; n < 5; ++n) {
        int col = n * 16 + lr;
        if (col < 72) {
            float bv = b0[col];
#pragma unroll
            for (int q = 0; q < 4; ++q) {
                int t = row_base + kg * 4 + q;
                if (t < N_NODES)
                    h4b[(size_t)t * 72 + col] = f2bf(fmaxf(acc[n][q] + bv, 0.f));
            }
        }
    }
}

// ---------------- MFMA MLP head + L2 normalize -----------------------------
#define HSTRIDE 136
__global__ __launch_bounds__(256) void mlp_k(const unsigned short* __restrict__ h5b,
                                             const unsigned short* __restrict__ w1t,
                                             const float* __restrict__ b1,
                                             const unsigned short* __restrict__ w2t,
                                             const float* __restrict__ b2,
                                             float* __restrict__ out) {
    __shared__ unsigned short sh[64 * HSTRIDE];
    int tid = threadIdx.x;
    int w = tid >> 6;
    int lane = tid & 63;
    int lr = lane & 15;
    int kg = lane >> 4;
    int row_base = blockIdx.x * 64 + w * 16;

    // ---- stage 1 ----
    f32x4 acc[8];
#pragma unroll
    for (int n = 0; n < 8; ++n) acc[n] = (f32x4){0.f, 0.f, 0.f, 0.f};

    const unsigned short* arow = h5b + (size_t)(row_base + lr) * 160 + kg * 8;
#pragma unroll
    for (int ks = 0; ks < 5; ++ks) {
        short8 a = *reinterpret_cast<const short8*>(arow + ks * 32);
#pragma unroll
        for (int n = 0; n < 8; ++n) {
            short8 b = *reinterpret_cast<const short8*>(w1t + (n * 16 + lr) * 160 + ks * 32 + kg * 8);
            acc[n] = __builtin_amdgcn_mfma_f32_16x16x32_bf16(a, b, acc[n], 0, 0, 0);
        }
    }
#pragma unroll
    for (int n = 0; n < 8; ++n) {
        float bv = b1[n * 16 + lr];
#pragma unroll
        for (int q = 0; q < 4; ++q) {
            float hv = fmaxf(acc[n][q] + bv, 0.f);
            sh[(w * 16 + kg * 4 + q) * HSTRIDE + n * 16 + lr] = f2bf(hv);
        }
    }
    __syncthreads();

    // ---- stage 2 ----
    f32x4 acc2[4];
#pragma unroll
    for (int n = 0; n < 4; ++n) acc2[n] = (f32x4){0.f, 0.f, 0.f, 0.f};
#pragma unroll
    for (int ks = 0; ks < 4; ++ks) {
        short8 a = *reinterpret_cast<const short8*>(sh + (w * 16 + lr) * HSTRIDE + ks * 32 + kg * 8);
#pragma unroll
        for (int n = 0; n < 4; ++n) {
            short8 b = *reinterpret_cast<const short8*>(w2t + (n * 16 + lr) * 128 + ks * 32 + kg * 8);
            acc2[n] = __builtin_amdgcn_mfma_f32_16x16x32_bf16(a, b, acc2[n], 0, 0, 0);
        }
    }

    float v[4][4];
    float ss[4];
#pragma unroll
    for (int q = 0; q < 4; ++q) ss[q] = 0.f;
#pragma unroll
    for (int n = 0; n < 4; ++n) {
        float bv = b2[n * 16 + lr];
#pragma unroll
        for (int q = 0; q < 4; ++q) {
            float x = acc2[n][q] + bv;
            v[n][q] = x;
            ss[q] += x * x;
        }
    }
#pragma unroll
    for (int q = 0; q < 4; ++q) {
#pragma unroll
        for (int d = 1; d < 16; d <<= 1) ss[q] += __shfl_xor(ss[q], d);
    }
#pragma unroll
    for (int q = 0; q < 4; ++q) {
        int node = row_base + kg * 4 + q;
        if (node < N_NODES) {
            float scale = 1.f / fmaxf(sqrtf(ss[q]), 1e-12f);
#pragma unroll
            for (int n = 0; n < 4; ++n)
                out[(size_t)node * 64 + n * 16 + lr] = v[n][q] * scale;
        }
    }
}

extern "C" void kernel_launch(void* const* d_in, const int* in_sizes, int n_in,
                              void* d_out, int out_size, void* d_ws, size_t ws_size,
                              hipStream_t stream) {
    const float* x   = (const float*)d_in[0];
    const float* kdd = (const float*)d_in[1];
    const float* kda = (const float*)d_in[2];
    const float* l0w = (const float*)d_in[3];
    const float* l0b = (const float*)d_in[4];
    const float* w1  = (const float*)d_in[5];
    const float* b1  = (const float*)d_in[6];
    const float* w2  = (const float*)d_in[7];
    const float* b2  = (const float*)d_in[8];
    const int*   src = (const int*)d_in[9];
    const int*   dst = (const int*)d_in[10];
    float* out = (float*)d_out;
    char* ws = (char*)d_ws;

    // workspace layout (bytes):
    //   rp    [0, +400004)
    //   w0t   [400384, +10240)        bf16 80x64
    //   w1t   [410624, +40960)        bf16 128x160
    //   w2t   [451584, +16384)        bf16 64x128
    //   hcb   [475136, +4.0 MB)       bf16 N*20
    //   h3b   [4480000, +12.80 MB)    bf16 100032*64 (K-padded)
    //   h4b   [17284096, +14.4 MB)    bf16 N*72
    //   h5b   [31684096, +32.01 MB)   bf16 100032*160
    int*   rp  = (int*)ws;
    unsigned short* w0t = (unsigned short*)(ws + 400384u);
    unsigned short* w1t = (unsigned short*)(ws + 410624u);
    unsigned short* w2t = (unsigned short*)(ws + 451584u);
    unsigned short* hcb = (unsigned short*)(ws + 475136u);
    unsigned short* h3b = (unsigned short*)(ws + 4480000u);
    unsigned short* h4b = (unsigned short*)(ws + 17284096u);
    unsigned short* h5b = (unsigned short*)(ws + 31684096u);

    rowptr_k<<<(N_NODES + 1 + 255) / 256, 256, 0, stream>>>(dst, rp);
    prep_k<<<(128 * 160 + 64 * 128 + 80 * 64 + 255) / 256, 256, 0, stream>>>(w1, w2, l0w, w1t, w2t, w0t);

    // DD phase: x[N,3] -> h1 (hcb cols 0:6) -> h2 (hcb cols 6:18)
    conv1_k<20><<<(N_NODES * 3 + 255) / 256, 256, 0, stream>>>(x, kdd, src, rp, hcb);
    convb_k<6, 2, 20, 20, 6, 0, 0><<<(N_NODES * 3 + 255) / 256, 256, 0, stream>>>(hcb, kdd, src, rp, hcb);

    // DA phase
    convb_k<18, 2, 20, 64, 0, 36, 64><<<(N_NODES * 9 + 255) / 256, 256, 0, stream>>>(hcb, kda, src, rp, h3b);
    lin0m_k<<<(N_NODES + 63) / 64, 256, 0, stream>>>(h3b, w0t, l0b, h4b);
    convb_k<72, 8, 72, 160, 0, 144, 160><<<(N_NODES * 9 + 255) / 256, 256, 0, stream>>>(h4b, kda, src, rp, h5b);

    // MFMA MLP head + normalize
    mlp_k<<<(N_NODES + 63) / 64, 256, 0, stream>>>(h5b, w1t, b1, w2t, b2, out);
}